// Round 7
// baseline (610.925 us; speedup 1.0000x reference)
//
#include <hip/hip_runtime.h>
#include <hip/hip_bf16.h>

#define T_STEPS 512
#define BATCH   256
#define FDIM    256
#define H1      128
#define H2      64
#define OUT_N   5
#define CHUNK   8
#define NCHUNK  (T_STEPS / CHUNK)
#define LOG2E   1.4426950408889634f

#if __has_builtin(__builtin_amdgcn_exp2f)
#define EXP2F(x) __builtin_amdgcn_exp2f(x)
#else
#define EXP2F(x) exp2f(x)
#endif
#if __has_builtin(__builtin_amdgcn_rcpf)
#define RCPF(x) __builtin_amdgcn_rcpf(x)
#else
#define RCPF(x) (1.0f / (x))
#endif

// Workgroup barrier WITHOUT vmcnt drain (m201-verified pattern): LDS ops
// ordered by lgkmcnt(0); global stores stay in flight across the barrier.
#define BAR() do {                                              \
    asm volatile("s_waitcnt lgkmcnt(0)" ::: "memory");          \
    __builtin_amdgcn_s_barrier();                               \
    __builtin_amdgcn_sched_barrier(0);                          \
} while (0)
// Chunk-end barrier: each wave drains its own vmem stores, then barrier ->
// after this, ALL waves' agent-scope stores are complete (release-safe).
#define VBAR() do {                                             \
    asm volatile("s_waitcnt vmcnt(0) lgkmcnt(0)" ::: "memory"); \
    __builtin_amdgcn_s_barrier();                               \
    __builtin_amdgcn_sched_barrier(0);                          \
} while (0)

// v + v(permuted) via DPP. 0xB1 = quad_perm xor1, 0x4E = quad_perm xor2,
// 0x141 = row_half_mirror (acts as xor4 once quads are uniform).
template<int CTRL>
__device__ __forceinline__ float dpp_add(float v) {
    int s = __builtin_amdgcn_update_dpp(0, __float_as_int(v), CTRL, 0xF, 0xF, true);
    return v + __int_as_float(s);
}
__device__ __forceinline__ float sig_scaled(float a) {   // a = -log2e*x
    return RCPF(1.0f + EXP2F(a));
}
__device__ __forceinline__ float tanh_scaled(float a) {  // a = 2log2e*u
    return fmaf(-2.0f, RCPF(EXP2F(a) + 1.0f), 1.0f);
}

// ---------------------------------------------------------------------------
// Kernel 1: xp[t][g] = scale_g*(b_ih1[g] + badd_g + sum_f x[t,255,f]*w_ih1[g,f])
// ---------------------------------------------------------------------------
__global__ __launch_bounds__(256) void xp1_kernel(
    const float* __restrict__ x,
    const float* __restrict__ w_ih1,
    const float* __restrict__ b_ih1,
    const float* __restrict__ b_hh1,
    float* __restrict__ xp)
{
    __shared__ float xrow[FDIM];
    const int t = blockIdx.x;
    const float* xr = x + (size_t)t * BATCH * FDIM + (size_t)(BATCH - 1) * FDIM;
    if (threadIdx.x < FDIM / 4) {
        ((float4*)xrow)[threadIdx.x] = ((const float4*)xr)[threadIdx.x];
    }
    __syncthreads();
    const int q = threadIdx.x >> 2;
    const int s = threadIdx.x & 3;
    #pragma unroll
    for (int pass = 0; pass < 6; ++pass) {
        const int g = pass * 64 + q;
        const float* w = w_ih1 + (size_t)g * FDIM + (s << 2);
        float acc = 0.0f;
        #pragma unroll
        for (int c = 0; c < 16; ++c) {
            float4 wv = *(const float4*)(w + 16 * c);
            const float* xv = xrow + (s << 2) + 16 * c;
            acc = fmaf(wv.x, xv[0], acc);
            acc = fmaf(wv.y, xv[1], acc);
            acc = fmaf(wv.z, xv[2], acc);
            acc = fmaf(wv.w, xv[3], acc);
        }
        acc = dpp_add<0xB1>(acc);
        acc = dpp_add<0x4E>(acc);
        if (s == 0) {
            const bool isN = (g >= 2 * H1);
            const float badd  = isN ? 0.0f : b_hh1[g];
            const float scale = isN ? (2.0f * LOG2E) : (-LOG2E);
            xp[t * (3 * H1) + g] = scale * (acc + b_ih1[g] + badd);
        }
    }
}

// ---------------------------------------------------------------------------
// Kernel 2: 2-block producer/consumer pipeline (structure identical to R6;
// wait discipline fixed: lgkm-only barriers in-loop, one vmcnt drain per
// 8-step chunk, fire-and-forget global stores).
// ---------------------------------------------------------------------------
__global__ __launch_bounds__(512) void gru_pipe_kernel(
    const float* __restrict__ xp,
    const float* __restrict__ w_hh1, const float* __restrict__ b_hh1,
    const float* __restrict__ w_ih2, const float* __restrict__ b_ih2,
    const float* __restrict__ w_hh2, const float* __restrict__ b_hh2,
    float* __restrict__ g_h1, unsigned int* __restrict__ flags,
    float* __restrict__ h2_all)
{
    __shared__ float h1d[2][H1];          // block 0
    __shared__ float h1chunk[CHUNK * H1]; // block 1
    __shared__ float h2d[2][H2];          // block 1
    const int tid = threadIdx.x;
    const float sRZ = -LOG2E, sN = 2.0f * LOG2E;

    if (blockIdx.x == 0) {
        // ========================= LAYER-1 PRODUCER =========================
        const int g  = tid >> 3;          // row pair: rows 2g, 2g+1
        const int s  = tid & 7;           // K-slice: k = 4s + 32c, c<4
        const int hi = (tid >> 2) & 1;    // which row this lane's gates do
        const int r0 = 2 * g;

        float wr0[16], wz0[16], wn0[16], wr1[16], wz1[16], wn1[16];
        {
            const float* br0 = w_hh1 + (size_t)(         r0) * H1;
            const float* bz0 = w_hh1 + (size_t)(H1     + r0) * H1;
            const float* bn0 = w_hh1 + (size_t)(2 * H1 + r0) * H1;
            #pragma unroll
            for (int c = 0; c < 4; c++) {
                const int kk = (s << 2) + 32 * c;
                float4 v0 = *(const float4*)(br0 + kk);
                float4 v1 = *(const float4*)(bz0 + kk);
                float4 v2 = *(const float4*)(bn0 + kk);
                float4 v3 = *(const float4*)(br0 + H1 + kk);
                float4 v4 = *(const float4*)(bz0 + H1 + kk);
                float4 v5 = *(const float4*)(bn0 + H1 + kk);
                wr0[4*c+0]=sRZ*v0.x; wr0[4*c+1]=sRZ*v0.y; wr0[4*c+2]=sRZ*v0.z; wr0[4*c+3]=sRZ*v0.w;
                wz0[4*c+0]=sRZ*v1.x; wz0[4*c+1]=sRZ*v1.y; wz0[4*c+2]=sRZ*v1.z; wz0[4*c+3]=sRZ*v1.w;
                wn0[4*c+0]=sN *v2.x; wn0[4*c+1]=sN *v2.y; wn0[4*c+2]=sN *v2.z; wn0[4*c+3]=sN *v2.w;
                wr1[4*c+0]=sRZ*v3.x; wr1[4*c+1]=sRZ*v3.y; wr1[4*c+2]=sRZ*v3.z; wr1[4*c+3]=sRZ*v3.w;
                wz1[4*c+0]=sRZ*v4.x; wz1[4*c+1]=sRZ*v4.y; wz1[4*c+2]=sRZ*v4.z; wz1[4*c+3]=sRZ*v4.w;
                wn1[4*c+0]=sN *v5.x; wn1[4*c+1]=sN *v5.y; wn1[4*c+2]=sN *v5.z; wn1[4*c+3]=sN *v5.w;
            }
        }
        const float bn_a = sN * b_hh1[2 * H1 + r0];
        const float bn_b = sN * b_hh1[2 * H1 + r0 + 1];
        const float bh1n_s = hi ? bn_b : bn_a;

        if (tid < H1) { h1d[0][tid] = 0.0f; h1d[1][tid] = 0.0f; }
        float h1prev = 0.0f;
        float cxr, cxz, cxn;
        {
            float2 a2 = *(const float2*)(xp + r0);
            float2 b2 = *(const float2*)(xp + H1 + r0);
            float2 c2 = *(const float2*)(xp + 2 * H1 + r0);
            cxr = hi ? a2.y : a2.x; cxz = hi ? b2.y : b2.x; cxn = hi ? c2.y : c2.x;
        }
        BAR();

        #pragma unroll 1
        for (int c = 0; c < NCHUNK; ++c) {
            #pragma unroll
            for (int i = 0; i < CHUNK; ++i) {
                const int k = c * CHUNK + i;
                const float* RP = h1d[(i + 1) & 1];
                float*       WP = h1d[i & 1];
                const float* hp = RP + (s << 2);
                float ar0=0.f, az0=0.f, an0=0.f, ar1=0.f, az1=0.f, an1=0.f;
                #pragma unroll
                for (int cc = 0; cc < 4; cc++) {
                    float4 h4 = *(const float4*)(hp + 32 * cc);
                    ar0=fmaf(wr0[4*cc+0],h4.x,ar0); az0=fmaf(wz0[4*cc+0],h4.x,az0); an0=fmaf(wn0[4*cc+0],h4.x,an0);
                    ar1=fmaf(wr1[4*cc+0],h4.x,ar1); az1=fmaf(wz1[4*cc+0],h4.x,az1); an1=fmaf(wn1[4*cc+0],h4.x,an1);
                    ar0=fmaf(wr0[4*cc+1],h4.y,ar0); az0=fmaf(wz0[4*cc+1],h4.y,az0); an0=fmaf(wn0[4*cc+1],h4.y,an0);
                    ar1=fmaf(wr1[4*cc+1],h4.y,ar1); az1=fmaf(wz1[4*cc+1],h4.y,az1); an1=fmaf(wn1[4*cc+1],h4.y,an1);
                    ar0=fmaf(wr0[4*cc+2],h4.z,ar0); az0=fmaf(wz0[4*cc+2],h4.z,az0); an0=fmaf(wn0[4*cc+2],h4.z,an0);
                    ar1=fmaf(wr1[4*cc+2],h4.z,ar1); az1=fmaf(wz1[4*cc+2],h4.z,az1); an1=fmaf(wn1[4*cc+2],h4.z,an1);
                    ar0=fmaf(wr0[4*cc+3],h4.w,ar0); az0=fmaf(wz0[4*cc+3],h4.w,az0); an0=fmaf(wn0[4*cc+3],h4.w,an0);
                    ar1=fmaf(wr1[4*cc+3],h4.w,ar1); az1=fmaf(wz1[4*cc+3],h4.w,az1); an1=fmaf(wn1[4*cc+3],h4.w,an1);
                }
                // prefetch next xp row (clamped); consumed next step, waited
                // by compiler-inserted vmcnt at use (no barrier drain).
                float2 a2, b2, c2;
                {
                    const int kn = (k < T_STEPS - 1) ? (k + 1) : (T_STEPS - 1);
                    const float* nx = xp + (size_t)kn * (3 * H1);
                    a2 = *(const float2*)(nx + r0);
                    b2 = *(const float2*)(nx + H1 + r0);
                    c2 = *(const float2*)(nx + 2 * H1 + r0);
                }
                ar0=dpp_add<0xB1>(ar0); ar0=dpp_add<0x4E>(ar0); ar0=dpp_add<0x141>(ar0);
                az0=dpp_add<0xB1>(az0); az0=dpp_add<0x4E>(az0); az0=dpp_add<0x141>(az0);
                an0=dpp_add<0xB1>(an0); an0=dpp_add<0x4E>(an0); an0=dpp_add<0x141>(an0);
                ar1=dpp_add<0xB1>(ar1); ar1=dpp_add<0x4E>(ar1); ar1=dpp_add<0x141>(ar1);
                az1=dpp_add<0xB1>(az1); az1=dpp_add<0x4E>(az1); az1=dpp_add<0x141>(az1);
                an1=dpp_add<0xB1>(an1); an1=dpp_add<0x4E>(an1); an1=dpp_add<0x141>(an1);
                const float ar = hi ? ar1 : ar0;
                const float az = hi ? az1 : az0;
                const float an = hi ? an1 : an0;
                const float r1g = sig_scaled(cxr + ar);
                const float z1g = sig_scaled(cxz + az);
                const float n1g = tanh_scaled(fmaf(r1g, an + bh1n_s, cxn));
                const float h1new = fmaf(z1g, h1prev - n1g, n1g);
                h1prev = h1new;
                if ((tid & 3) == 0) {
                    WP[r0 + hi] = h1new;
                    __hip_atomic_store((unsigned int*)g_h1 + (size_t)k * H1 + r0 + hi,
                                       __float_as_uint(h1new),
                                       __ATOMIC_RELAXED, __HIP_MEMORY_SCOPE_AGENT);
                }
                cxr = hi ? a2.y : a2.x; cxz = hi ? b2.y : b2.x; cxn = hi ? c2.y : c2.x;
                if (i == CHUNK - 1) {
                    VBAR();   // all waves' g_h1 stores complete after this
                    if (tid == 0) {
                        __hip_atomic_store(&flags[c], 1u,
                                           __ATOMIC_RELEASE, __HIP_MEMORY_SCOPE_AGENT);
                    }
                } else {
                    BAR();
                }
            }
        }
    } else {
        // ========================= LAYER-2 CONSUMER =========================
        const int j2 = tid >> 3, s2 = tid & 7;
        float w2r[24], w2z[24], w2n[24];
        {
            const float* ir  = w_ih2 + (size_t)(         j2) * H1;
            const float* iz  = w_ih2 + (size_t)(H2     + j2) * H1;
            const float* inn = w_ih2 + (size_t)(2 * H2 + j2) * H1;
            #pragma unroll
            for (int c = 0; c < 4; c++) {
                const int kk = (s2 << 2) + 32 * c;
                float4 vr = *(const float4*)(ir  + kk);
                float4 vz = *(const float4*)(iz  + kk);
                float4 vn = *(const float4*)(inn + kk);
                w2r[4*c+0]=sRZ*vr.x; w2r[4*c+1]=sRZ*vr.y; w2r[4*c+2]=sRZ*vr.z; w2r[4*c+3]=sRZ*vr.w;
                w2z[4*c+0]=sRZ*vz.x; w2z[4*c+1]=sRZ*vz.y; w2z[4*c+2]=sRZ*vz.z; w2z[4*c+3]=sRZ*vz.w;
                w2n[4*c+0]=sN *vn.x; w2n[4*c+1]=sN *vn.y; w2n[4*c+2]=sN *vn.z; w2n[4*c+3]=sN *vn.w;
            }
            const float* hr = w_hh2 + (size_t)(         j2) * H2;
            const float* hz = w_hh2 + (size_t)(H2     + j2) * H2;
            const float* hn = w_hh2 + (size_t)(2 * H2 + j2) * H2;
            #pragma unroll
            for (int c = 0; c < 2; c++) {
                const int kk = (s2 << 2) + 32 * c;
                const int o = 4 * (c + 4);
                float4 vr = *(const float4*)(hr + kk);
                float4 vz = *(const float4*)(hz + kk);
                float4 vn = *(const float4*)(hn + kk);
                w2r[o+0]=sRZ*vr.x; w2r[o+1]=sRZ*vr.y; w2r[o+2]=sRZ*vr.z; w2r[o+3]=sRZ*vr.w;
                w2z[o+0]=sRZ*vz.x; w2z[o+1]=sRZ*vz.y; w2z[o+2]=sRZ*vz.z; w2z[o+3]=sRZ*vz.w;
                w2n[o+0]=sN *vn.x; w2n[o+1]=sN *vn.y; w2n[o+2]=sN *vn.z; w2n[o+3]=sN *vn.w;
            }
        }
        const float b2r_s  = sRZ * (b_ih2[j2]      + b_hh2[j2]);
        const float b2z_s  = sRZ * (b_ih2[H2 + j2] + b_hh2[H2 + j2]);
        const float b2xn_s = sN  *  b_ih2[2 * H2 + j2];
        const float b2hn_s = sN  *  b_hh2[2 * H2 + j2];
        float h2prev = 0.0f;
        if (tid < H2) { h2d[0][tid] = 0.0f; h2d[1][tid] = 0.0f; }
        BAR();

        #pragma unroll 1
        for (int c = 0; c < NCHUNK; ++c) {
            while (__hip_atomic_load(&flags[c], __ATOMIC_ACQUIRE,
                                     __HIP_MEMORY_SCOPE_AGENT) != 1u) {
                __builtin_amdgcn_s_sleep(1);
            }
            unsigned long long v = __hip_atomic_load(
                (const unsigned long long*)g_h1 + (size_t)c * 512 + tid,
                __ATOMIC_RELAXED, __HIP_MEMORY_SCOPE_AGENT);
            ((unsigned long long*)h1chunk)[tid] = v;
            BAR();

            #pragma unroll
            for (int i = 0; i < CHUNK; ++i) {
                const int t = c * CHUNK + i;
                const float* g1p = h1chunk + i * H1 + (s2 << 2);
                const float* g2p = h2d[(i + 1) & 1] + (s2 << 2);
                float a2r = 0.f, a2z = 0.f, axn = 0.f, ahn = 0.f;
                #pragma unroll
                for (int cc = 0; cc < 4; cc++) {
                    float4 g4 = *(const float4*)(g1p + 32 * cc);
                    a2r=fmaf(w2r[4*cc+0],g4.x,a2r); a2z=fmaf(w2z[4*cc+0],g4.x,a2z); axn=fmaf(w2n[4*cc+0],g4.x,axn);
                    a2r=fmaf(w2r[4*cc+1],g4.y,a2r); a2z=fmaf(w2z[4*cc+1],g4.y,a2z); axn=fmaf(w2n[4*cc+1],g4.y,axn);
                    a2r=fmaf(w2r[4*cc+2],g4.z,a2r); a2z=fmaf(w2z[4*cc+2],g4.z,a2z); axn=fmaf(w2n[4*cc+2],g4.z,axn);
                    a2r=fmaf(w2r[4*cc+3],g4.w,a2r); a2z=fmaf(w2z[4*cc+3],g4.w,a2z); axn=fmaf(w2n[4*cc+3],g4.w,axn);
                }
                #pragma unroll
                for (int cc = 4; cc < 6; cc++) {
                    float4 g4 = *(const float4*)(g2p + 32 * (cc - 4));
                    a2r=fmaf(w2r[4*cc+0],g4.x,a2r); a2z=fmaf(w2z[4*cc+0],g4.x,a2z); ahn=fmaf(w2n[4*cc+0],g4.x,ahn);
                    a2r=fmaf(w2r[4*cc+1],g4.y,a2r); a2z=fmaf(w2z[4*cc+1],g4.y,a2z); ahn=fmaf(w2n[4*cc+1],g4.y,ahn);
                    a2r=fmaf(w2r[4*cc+2],g4.z,a2r); a2z=fmaf(w2z[4*cc+2],g4.z,a2z); ahn=fmaf(w2n[4*cc+2],g4.z,ahn);
                    a2r=fmaf(w2r[4*cc+3],g4.w,a2r); a2z=fmaf(w2z[4*cc+3],g4.w,a2z); ahn=fmaf(w2n[4*cc+3],g4.w,ahn);
                }
                a2r=dpp_add<0xB1>(a2r); a2r=dpp_add<0x4E>(a2r); a2r=dpp_add<0x141>(a2r);
                a2z=dpp_add<0xB1>(a2z); a2z=dpp_add<0x4E>(a2z); a2z=dpp_add<0x141>(a2z);
                axn=dpp_add<0xB1>(axn); axn=dpp_add<0x4E>(axn); axn=dpp_add<0x141>(axn);
                ahn=dpp_add<0xB1>(ahn); ahn=dpp_add<0x4E>(ahn); ahn=dpp_add<0x141>(ahn);
                const float r2 = sig_scaled(a2r + b2r_s);
                const float z2 = sig_scaled(a2z + b2z_s);
                const float n2 = tanh_scaled(fmaf(r2, ahn + b2hn_s, axn + b2xn_s));
                const float h2new = fmaf(z2, h2prev - n2, n2);
                h2prev = h2new;
                if (s2 == 0) {
                    h2d[i & 1][j2] = h2new;
                    h2_all[(size_t)t * H2 + j2] = h2new;   // fire-and-forget
                }
                BAR();
            }
        }
    }
}

// ---------------------------------------------------------------------------
// Kernel 3: out[t][o] = lin_b[o] + sum_j h2_all[t][j] * lin_w[o][j]
// ---------------------------------------------------------------------------
__global__ __launch_bounds__(256) void head_kernel(
    const float* __restrict__ h2_all,
    const float* __restrict__ lin_w,
    const float* __restrict__ lin_b,
    float* __restrict__ out)
{
    const int t = blockIdx.x * blockDim.x + threadIdx.x;
    if (t >= T_STEPS) return;
    const float* h = h2_all + t * H2;
    #pragma unroll
    for (int o = 0; o < OUT_N; o++) {
        float acc = lin_b[o];
        const float* w = lin_w + o * H2;
        #pragma unroll
        for (int j = 0; j < H2; j += 4) {
            float4 wv = *(const float4*)(w + j);
            float4 hv = *(const float4*)(h + j);
            acc = fmaf(wv.x, hv.x, acc);
            acc = fmaf(wv.y, hv.y, acc);
            acc = fmaf(wv.z, hv.z, acc);
            acc = fmaf(wv.w, hv.w, acc);
        }
        out[t * OUT_N + o] = acc;
    }
}

extern "C" void kernel_launch(void* const* d_in, const int* in_sizes, int n_in,
                              void* d_out, int out_size, void* d_ws, size_t ws_size,
                              hipStream_t stream) {
    const float* x     = (const float*)d_in[0];
    const float* w_ih1 = (const float*)d_in[1];
    const float* w_hh1 = (const float*)d_in[2];
    const float* b_ih1 = (const float*)d_in[3];
    const float* b_hh1 = (const float*)d_in[4];
    const float* w_ih2 = (const float*)d_in[5];
    const float* w_hh2 = (const float*)d_in[6];
    const float* b_ih2 = (const float*)d_in[7];
    const float* b_hh2 = (const float*)d_in[8];
    const float* lin_w = (const float*)d_in[9];
    const float* lin_b = (const float*)d_in[10];
    float* out = (float*)d_out;

    float* xp        = (float*)d_ws;                    // 512*384
    float* h2_all    = xp + T_STEPS * 3 * H1;           // 512*64
    float* g_h1      = h2_all + T_STEPS * H2;           // 512*128
    unsigned int* fl = (unsigned int*)(g_h1 + T_STEPS * H1);  // 64 flags

    hipMemsetAsync(fl, 0, NCHUNK * sizeof(unsigned int), stream);
    xp1_kernel<<<T_STEPS, 256, 0, stream>>>(x, w_ih1, b_ih1, b_hh1, xp);
    gru_pipe_kernel<<<2, 512, 0, stream>>>(xp, w_hh1, b_hh1,
                                           w_ih2, b_ih2, w_hh2, b_hh2,
                                           g_h1, fl, h2_all);
    head_kernel<<<(T_STEPS + 255) / 256, 256, 0, stream>>>(h2_all, lin_w, lin_b, out);
}

// Round 8
// 535.896 us; speedup vs baseline: 1.1400x; 1.1400x over previous
//
#include <hip/hip_runtime.h>
#include <hip/hip_bf16.h>

#define T_STEPS 512
#define BATCH   256
#define FDIM    256
#define H1      128
#define H2      64
#define OUT_N   5
#define CAT     (H1 + H2)     // 192
#define LOG2E   1.4426950408889634f

#if __has_builtin(__builtin_amdgcn_exp2f)
#define EXP2F(x) __builtin_amdgcn_exp2f(x)
#else
#define EXP2F(x) exp2f(x)
#endif
#if __has_builtin(__builtin_amdgcn_rcpf)
#define RCPF(x) __builtin_amdgcn_rcpf(x)
#else
#define RCPF(x) (1.0f / (x))
#endif

// Workgroup barrier WITHOUT vmcnt drain: LDS ops ordered by lgkmcnt(0);
// global loads/stores (xp prefetch, h2_all store) stay in flight.
#define BAR() do {                                              \
    asm volatile("s_waitcnt lgkmcnt(0)" ::: "memory");          \
    __builtin_amdgcn_s_barrier();                               \
} while (0)

// v + v(permuted) via DPP. 0xB1 = quad_perm xor1, 0x4E = quad_perm xor2,
// 0x141 = row_half_mirror (acts as xor4 once quads are uniform).
template<int CTRL>
__device__ __forceinline__ float dpp_add(float v) {
    int s = __builtin_amdgcn_update_dpp(0, __float_as_int(v), CTRL, 0xF, 0xF, true);
    return v + __int_as_float(s);
}
__device__ __forceinline__ float sig_scaled(float a) {   // a = -log2e*x
    return RCPF(1.0f + EXP2F(a));
}
__device__ __forceinline__ float tanh_scaled(float a) {  // a = 2log2e*u
    return fmaf(-2.0f, RCPF(EXP2F(a) + 1.0f), 1.0f);
}

// ---------------------------------------------------------------------------
// Kernel 1: xp[t][g] = scale_g*(b_ih1[g] + badd_g + sum_f x[t,255,f]*w_ih1[g,f])
// ---------------------------------------------------------------------------
__global__ __launch_bounds__(256) void xp1_kernel(
    const float* __restrict__ x,
    const float* __restrict__ w_ih1,
    const float* __restrict__ b_ih1,
    const float* __restrict__ b_hh1,
    float* __restrict__ xp)
{
    __shared__ float xrow[FDIM];
    const int t = blockIdx.x;
    const float* xr = x + (size_t)t * BATCH * FDIM + (size_t)(BATCH - 1) * FDIM;
    if (threadIdx.x < FDIM / 4) {
        ((float4*)xrow)[threadIdx.x] = ((const float4*)xr)[threadIdx.x];
    }
    __syncthreads();
    const int q = threadIdx.x >> 2;
    const int s = threadIdx.x & 3;
    #pragma unroll
    for (int pass = 0; pass < 6; ++pass) {
        const int g = pass * 64 + q;
        const float* w = w_ih1 + (size_t)g * FDIM + (s << 2);
        float acc = 0.0f;
        #pragma unroll
        for (int c = 0; c < 16; ++c) {
            float4 wv = *(const float4*)(w + 16 * c);
            const float* xv = xrow + (s << 2) + 16 * c;
            acc = fmaf(wv.x, xv[0], acc);
            acc = fmaf(wv.y, xv[1], acc);
            acc = fmaf(wv.z, xv[2], acc);
            acc = fmaf(wv.w, xv[3], acc);
        }
        acc = dpp_add<0xB1>(acc);
        acc = dpp_add<0x4E>(acc);
        if (s == 0) {
            const bool isN = (g >= 2 * H1);
            const float badd  = isN ? 0.0f : b_hh1[g];
            const float scale = isN ? (2.0f * LOG2E) : (-LOG2E);
            xp[t * (3 * H1) + g] = scale * (acc + b_ih1[g] + badd);
        }
    }
}

// ---------------------------------------------------------------------------
// Kernel 2: single-CU, wave-specialized, 1024 thr = 16 waves.
// Waves 0-7: layer 1, G=2 row-pair layout (R6-verified math): 8 lanes per
//   row-pair, lane K-slice = 16 floats -> 4 ds_read_b128/thread (was 8 in R5).
// Waves 8-15: layer 2, G=1 (R5-verified math): 8 lanes/row over concat
//   [h1;h2], 6 ds_read_b128/thread.
// DS pipe/step: (8*4 + 8*6) b128 x ~12cyc = 960 cyc (R5: 1344) -> balanced
// with VALU (~1040/SIMD). One lgkm-only barrier per step (no vmcnt drain:
// xp prefetch + h2_all stores stay in flight). h_old carried in registers.
// Software-pipelined: slot k = L1 makes h1[k] || L2 makes h2[k-1]; both
// read cat[prev] only, write cat[cur] only. 514 barriers per branch.
// ---------------------------------------------------------------------------
__global__ __launch_bounds__(1024) void gru_seq_kernel(
    const float* __restrict__ xp,
    const float* __restrict__ w_hh1, const float* __restrict__ b_hh1,
    const float* __restrict__ w_ih2, const float* __restrict__ b_ih2,
    const float* __restrict__ w_hh2, const float* __restrict__ b_hh2,
    float* __restrict__ h2_all)
{
    const int tid = threadIdx.x;
    __shared__ float cat0[CAT];   // [h1(128); h2(64)], written at even k
    __shared__ float cat1[CAT];   // written at odd k
    if (tid < CAT) { cat0[tid] = 0.0f; cat1[tid] = 0.0f; }

    const float sRZ = -LOG2E, sN = 2.0f * LOG2E;

    if (tid < 512) {
        // ============== LAYER-1 WAVES (G=2 row-pair, R6 math) ==============
        const int g  = tid >> 3;          // row pair: rows 2g, 2g+1
        const int s  = tid & 7;           // K-slice: k = 4s + 32c, c<4
        const int hi = (tid >> 2) & 1;    // which row this lane's gates do
        const int r0 = 2 * g;

        float wr0[16], wz0[16], wn0[16], wr1[16], wz1[16], wn1[16];
        {
            const float* br0 = w_hh1 + (size_t)(         r0) * H1;
            const float* bz0 = w_hh1 + (size_t)(H1     + r0) * H1;
            const float* bn0 = w_hh1 + (size_t)(2 * H1 + r0) * H1;
            #pragma unroll
            for (int c = 0; c < 4; c++) {
                const int kk = (s << 2) + 32 * c;
                float4 v0 = *(const float4*)(br0 + kk);
                float4 v1 = *(const float4*)(bz0 + kk);
                float4 v2 = *(const float4*)(bn0 + kk);
                float4 v3 = *(const float4*)(br0 + H1 + kk);
                float4 v4 = *(const float4*)(bz0 + H1 + kk);
                float4 v5 = *(const float4*)(bn0 + H1 + kk);
                wr0[4*c+0]=sRZ*v0.x; wr0[4*c+1]=sRZ*v0.y; wr0[4*c+2]=sRZ*v0.z; wr0[4*c+3]=sRZ*v0.w;
                wz0[4*c+0]=sRZ*v1.x; wz0[4*c+1]=sRZ*v1.y; wz0[4*c+2]=sRZ*v1.z; wz0[4*c+3]=sRZ*v1.w;
                wn0[4*c+0]=sN *v2.x; wn0[4*c+1]=sN *v2.y; wn0[4*c+2]=sN *v2.z; wn0[4*c+3]=sN *v2.w;
                wr1[4*c+0]=sRZ*v3.x; wr1[4*c+1]=sRZ*v3.y; wr1[4*c+2]=sRZ*v3.z; wr1[4*c+3]=sRZ*v3.w;
                wz1[4*c+0]=sRZ*v4.x; wz1[4*c+1]=sRZ*v4.y; wz1[4*c+2]=sRZ*v4.z; wz1[4*c+3]=sRZ*v4.w;
                wn1[4*c+0]=sN *v5.x; wn1[4*c+1]=sN *v5.y; wn1[4*c+2]=sN *v5.z; wn1[4*c+3]=sN *v5.w;
            }
        }
        const float bn_a = sN * b_hh1[2 * H1 + r0];
        const float bn_b = sN * b_hh1[2 * H1 + r0 + 1];
        const float bh1n_s = hi ? bn_b : bn_a;

        float h1prev = 0.0f;
        float cxr, cxz, cxn;
        {
            float2 a2 = *(const float2*)(xp + r0);
            float2 b2 = *(const float2*)(xp + H1 + r0);
            float2 c2 = *(const float2*)(xp + 2 * H1 + r0);
            cxr = hi ? a2.y : a2.x; cxz = hi ? b2.y : b2.x; cxn = hi ? c2.y : c2.x;
        }
        BAR();   // [init]

        #define L1_BODY(RP, WP, K) do {                                                 \
            const float* hp = RP + (s << 2);                                            \
            float ar0=0.f, az0=0.f, an0=0.f, ar1=0.f, az1=0.f, an1=0.f;                 \
            _Pragma("unroll")                                                           \
            for (int cc = 0; cc < 4; cc++) {                                            \
                float4 h4 = *(const float4*)(hp + 32 * cc);                             \
                ar0=fmaf(wr0[4*cc+0],h4.x,ar0); az0=fmaf(wz0[4*cc+0],h4.x,az0); an0=fmaf(wn0[4*cc+0],h4.x,an0); \
                ar1=fmaf(wr1[4*cc+0],h4.x,ar1); az1=fmaf(wz1[4*cc+0],h4.x,az1); an1=fmaf(wn1[4*cc+0],h4.x,an1); \
                ar0=fmaf(wr0[4*cc+1],h4.y,ar0); az0=fmaf(wz0[4*cc+1],h4.y,az0); an0=fmaf(wn0[4*cc+1],h4.y,an0); \
                ar1=fmaf(wr1[4*cc+1],h4.y,ar1); az1=fmaf(wz1[4*cc+1],h4.y,az1); an1=fmaf(wn1[4*cc+1],h4.y,an1); \
                ar0=fmaf(wr0[4*cc+2],h4.z,ar0); az0=fmaf(wz0[4*cc+2],h4.z,az0); an0=fmaf(wn0[4*cc+2],h4.z,an0); \
                ar1=fmaf(wr1[4*cc+2],h4.z,ar1); az1=fmaf(wz1[4*cc+2],h4.z,az1); an1=fmaf(wn1[4*cc+2],h4.z,an1); \
                ar0=fmaf(wr0[4*cc+3],h4.w,ar0); az0=fmaf(wz0[4*cc+3],h4.w,az0); an0=fmaf(wn0[4*cc+3],h4.w,an0); \
                ar1=fmaf(wr1[4*cc+3],h4.w,ar1); az1=fmaf(wz1[4*cc+3],h4.w,az1); an1=fmaf(wn1[4*cc+3],h4.w,an1); \
            }                                                                           \
            float2 a2, b2, c2;                                                          \
            {                                                                           \
                const int kn = ((K) < T_STEPS - 1) ? ((K) + 1) : (T_STEPS - 1);         \
                const float* nx = xp + (size_t)kn * (3 * H1);                           \
                a2 = *(const float2*)(nx + r0);                                         \
                b2 = *(const float2*)(nx + H1 + r0);                                    \
                c2 = *(const float2*)(nx + 2 * H1 + r0);                                \
            }                                                                           \
            ar0=dpp_add<0xB1>(ar0); ar0=dpp_add<0x4E>(ar0); ar0=dpp_add<0x141>(ar0);    \
            az0=dpp_add<0xB1>(az0); az0=dpp_add<0x4E>(az0); az0=dpp_add<0x141>(az0);    \
            an0=dpp_add<0xB1>(an0); an0=dpp_add<0x4E>(an0); an0=dpp_add<0x141>(an0);    \
            ar1=dpp_add<0xB1>(ar1); ar1=dpp_add<0x4E>(ar1); ar1=dpp_add<0x141>(ar1);    \
            az1=dpp_add<0xB1>(az1); az1=dpp_add<0x4E>(az1); az1=dpp_add<0x141>(az1);    \
            an1=dpp_add<0xB1>(an1); an1=dpp_add<0x4E>(an1); an1=dpp_add<0x141>(an1);    \
            const float ar = hi ? ar1 : ar0;                                            \
            const float az = hi ? az1 : az0;                                            \
            const float an = hi ? an1 : an0;                                            \
            const float r1g = sig_scaled(cxr + ar);                                     \
            const float z1g = sig_scaled(cxz + az);                                     \
            const float n1g = tanh_scaled(fmaf(r1g, an + bh1n_s, cxn));                 \
            const float h1new = fmaf(z1g, h1prev - n1g, n1g);                           \
            h1prev = h1new;                                                             \
            if ((tid & 3) == 0) WP[r0 + hi] = h1new;                                    \
            cxr = hi ? a2.y : a2.x; cxz = hi ? b2.y : b2.x; cxn = hi ? c2.y : c2.x;     \
        } while (0)

        #pragma unroll 1
        for (int i = 0; i < 256; i++) {       // slots k = 2i (even), 2i+1 (odd)
            L1_BODY(cat1, cat0, 2 * i);
            BAR();
            L1_BODY(cat0, cat1, 2 * i + 1);
            BAR();
        }
        BAR();                                 // slot 512 (L2's last)
        #undef L1_BODY
    } else {
        // ============== LAYER-2 WAVES (G=1, R5 math) =======================
        const int t2 = tid - 512;
        const int j2 = t2 >> 3, s2 = t2 & 7;
        float w2r[24], w2z[24], w2n[24];
        {
            const float* ir  = w_ih2 + (size_t)(         j2) * H1;
            const float* iz  = w_ih2 + (size_t)(H2     + j2) * H1;
            const float* inn = w_ih2 + (size_t)(2 * H2 + j2) * H1;
            #pragma unroll
            for (int c = 0; c < 4; c++) {
                const int kk = (s2 << 2) + 32 * c;
                float4 vr = *(const float4*)(ir  + kk);
                float4 vz = *(const float4*)(iz  + kk);
                float4 vn = *(const float4*)(inn + kk);
                w2r[4*c+0]=sRZ*vr.x; w2r[4*c+1]=sRZ*vr.y; w2r[4*c+2]=sRZ*vr.z; w2r[4*c+3]=sRZ*vr.w;
                w2z[4*c+0]=sRZ*vz.x; w2z[4*c+1]=sRZ*vz.y; w2z[4*c+2]=sRZ*vz.z; w2z[4*c+3]=sRZ*vz.w;
                w2n[4*c+0]=sN *vn.x; w2n[4*c+1]=sN *vn.y; w2n[4*c+2]=sN *vn.z; w2n[4*c+3]=sN *vn.w;
            }
            const float* hr = w_hh2 + (size_t)(         j2) * H2;
            const float* hz = w_hh2 + (size_t)(H2     + j2) * H2;
            const float* hn = w_hh2 + (size_t)(2 * H2 + j2) * H2;
            #pragma unroll
            for (int c = 0; c < 2; c++) {
                const int kk = (s2 << 2) + 32 * c;
                const int o = 4 * (c + 4);
                float4 vr = *(const float4*)(hr + kk);
                float4 vz = *(const float4*)(hz + kk);
                float4 vn = *(const float4*)(hn + kk);
                w2r[o+0]=sRZ*vr.x; w2r[o+1]=sRZ*vr.y; w2r[o+2]=sRZ*vr.z; w2r[o+3]=sRZ*vr.w;
                w2z[o+0]=sRZ*vz.x; w2z[o+1]=sRZ*vz.y; w2z[o+2]=sRZ*vz.z; w2z[o+3]=sRZ*vz.w;
                w2n[o+0]=sN *vn.x; w2n[o+1]=sN *vn.y; w2n[o+2]=sN *vn.z; w2n[o+3]=sN *vn.w;
            }
        }
        const float b2r_s  = sRZ * (b_ih2[j2]      + b_hh2[j2]);
        const float b2z_s  = sRZ * (b_ih2[H2 + j2] + b_hh2[H2 + j2]);
        const float b2xn_s = sN  *  b_ih2[2 * H2 + j2];
        const float b2hn_s = sN  *  b_hh2[2 * H2 + j2];
        float h2prev = 0.0f;
        float* hout = h2_all + j2;
        BAR();   // [init]
        BAR();   // slot 0 (no L2 work)

        #define L2_BODY(RP, WP) do {                                                    \
            const float* gp = RP + (s2 << 2);                                           \
            float a2r = 0.f, a2z = 0.f, axn = 0.f, ahn = 0.f;                           \
            _Pragma("unroll")                                                           \
            for (int cc = 0; cc < 4; cc++) {                                            \
                float4 g4 = *(const float4*)(gp + 32 * cc);                             \
                a2r=fmaf(w2r[4*cc+0],g4.x,a2r); a2z=fmaf(w2z[4*cc+0],g4.x,a2z); axn=fmaf(w2n[4*cc+0],g4.x,axn); \
                a2r=fmaf(w2r[4*cc+1],g4.y,a2r); a2z=fmaf(w2z[4*cc+1],g4.y,a2z); axn=fmaf(w2n[4*cc+1],g4.y,axn); \
                a2r=fmaf(w2r[4*cc+2],g4.z,a2r); a2z=fmaf(w2z[4*cc+2],g4.z,a2z); axn=fmaf(w2n[4*cc+2],g4.z,axn); \
                a2r=fmaf(w2r[4*cc+3],g4.w,a2r); a2z=fmaf(w2z[4*cc+3],g4.w,a2z); axn=fmaf(w2n[4*cc+3],g4.w,axn); \
            }                                                                           \
            _Pragma("unroll")                                                           \
            for (int cc = 4; cc < 6; cc++) {                                            \
                float4 g4 = *(const float4*)(gp + 32 * cc);                             \
                a2r=fmaf(w2r[4*cc+0],g4.x,a2r); a2z=fmaf(w2z[4*cc+0],g4.x,a2z); ahn=fmaf(w2n[4*cc+0],g4.x,ahn); \
                a2r=fmaf(w2r[4*cc+1],g4.y,a2r); a2z=fmaf(w2z[4*cc+1],g4.y,a2z); ahn=fmaf(w2n[4*cc+1],g4.y,ahn); \
                a2r=fmaf(w2r[4*cc+2],g4.z,a2r); a2z=fmaf(w2z[4*cc+2],g4.z,a2z); ahn=fmaf(w2n[4*cc+2],g4.z,ahn); \
                a2r=fmaf(w2r[4*cc+3],g4.w,a2r); a2z=fmaf(w2z[4*cc+3],g4.w,a2z); ahn=fmaf(w2n[4*cc+3],g4.w,ahn); \
            }                                                                           \
            a2r=dpp_add<0xB1>(a2r); a2r=dpp_add<0x4E>(a2r); a2r=dpp_add<0x141>(a2r);    \
            a2z=dpp_add<0xB1>(a2z); a2z=dpp_add<0x4E>(a2z); a2z=dpp_add<0x141>(a2z);    \
            axn=dpp_add<0xB1>(axn); axn=dpp_add<0x4E>(axn); axn=dpp_add<0x141>(axn);    \
            ahn=dpp_add<0xB1>(ahn); ahn=dpp_add<0x4E>(ahn); ahn=dpp_add<0x141>(ahn);    \
            const float r2 = sig_scaled(a2r + b2r_s);                                   \
            const float z2 = sig_scaled(a2z + b2z_s);                                   \
            const float n2 = tanh_scaled(fmaf(r2, ahn + b2hn_s, axn + b2xn_s));         \
            const float h2new = fmaf(z2, h2prev - n2, n2);                              \
            h2prev = h2new;                                                             \
            if (s2 == 0) { WP[H1 + j2] = h2new; *hout = h2new; }                        \
            hout += H2;                                                                 \
        } while (0)

        #pragma unroll 1
        for (int i = 0; i < 256; i++) {       // slots k = 2i+1, 2i+2
            L2_BODY(cat0, cat1);
            BAR();
            L2_BODY(cat1, cat0);
            BAR();
        }
        #undef L2_BODY
    }
}

// ---------------------------------------------------------------------------
// Kernel 3: out[t][o] = lin_b[o] + sum_j h2_all[t][j] * lin_w[o][j]
// ---------------------------------------------------------------------------
__global__ __launch_bounds__(256) void head_kernel(
    const float* __restrict__ h2_all,
    const float* __restrict__ lin_w,
    const float* __restrict__ lin_b,
    float* __restrict__ out)
{
    const int t = blockIdx.x * blockDim.x + threadIdx.x;
    if (t >= T_STEPS) return;
    const float* h = h2_all + t * H2;
    #pragma unroll
    for (int o = 0; o < OUT_N; o++) {
        float acc = lin_b[o];
        const float* w = lin_w + o * H2;
        #pragma unroll
        for (int j = 0; j < H2; j += 4) {
            float4 wv = *(const float4*)(w + j);
            float4 hv = *(const float4*)(h + j);
            acc = fmaf(wv.x, hv.x, acc);
            acc = fmaf(wv.y, hv.y, acc);
            acc = fmaf(wv.z, hv.z, acc);
            acc = fmaf(wv.w, hv.w, acc);
        }
        out[t * OUT_N + o] = acc;
    }
}

extern "C" void kernel_launch(void* const* d_in, const int* in_sizes, int n_in,
                              void* d_out, int out_size, void* d_ws, size_t ws_size,
                              hipStream_t stream) {
    const float* x     = (const float*)d_in[0];
    const float* w_ih1 = (const float*)d_in[1];
    const float* w_hh1 = (const float*)d_in[2];
    const float* b_ih1 = (const float*)d_in[3];
    const float* b_hh1 = (const float*)d_in[4];
    const float* w_ih2 = (const float*)d_in[5];
    const float* w_hh2 = (const float*)d_in[6];
    const float* b_ih2 = (const float*)d_in[7];
    const float* b_hh2 = (const float*)d_in[8];
    const float* lin_w = (const float*)d_in[9];
    const float* lin_b = (const float*)d_in[10];
    float* out = (float*)d_out;

    float* xp     = (float*)d_ws;                  // 512*384 floats (pre-scaled)
    float* h2_all = xp + T_STEPS * 3 * H1;         // 512*64 floats

    xp1_kernel<<<T_STEPS, 256, 0, stream>>>(x, w_ih1, b_ih1, b_hh1, xp);
    gru_seq_kernel<<<1, 1024, 0, stream>>>(xp, w_hh1, b_hh1,
                                           w_ih2, b_ih2, w_hh2, b_hh2, h2_all);
    head_kernel<<<(T_STEPS + 255) / 256, 256, 0, stream>>>(h2_all, lin_w, lin_b, out);
}